// Round 2
// baseline (3187.097 us; speedup 1.0000x reference)
//
#include <hip/hip_runtime.h>
#include <math.h>

// ExactContinuousSBM: reverse VP-SDE sampling of a Gaussian mixture.
// Round 2: k-split across lanes for 4x occupancy + two-pass softmax.
//
// Layout: 1024 blocks x 256 threads (4 waves). Each wave: 2 batch elems x
// 32 lanes; lane bits [0:2]=d-chunk (4 dims), [3:4]=k-group (16 k each),
// [5]=b-slot. Two-pass softmax: pass1 = logc + max (no exp), cross-kg max
// via DPP row_mirror + ds_swizzle xor16; pass2 = exp2 + plain FMA accum;
// kg-merge of (L,SIV,SA) via ds_swizzle xor8/xor16 adds.
// All constants pre-scaled by log2(e) so exp = single v_exp_f32.
// LDS double-buffered; const-gen for step j+1 pipelined inside step j
// -> one barrier per step.

namespace {

constexpr int BD   = 8192;
constexpr int DIMN = 32;
constexpr int KM   = 64;
constexpr int NST  = 255;
constexpr float TMINc = 1e-4f, TMAXc = 1.0f;
constexpr float BMIN = 0.1f,  BMAX = 20.0f;
constexpr float L2E = 1.4426950408889634f;   // log2(e)
constexpr float LN2 = 0.6931471805599453f;   // 1/log2(e)

// DPP helpers. 0xB1=quad_perm xor1, 0x4E=quad_perm xor2,
// 0x141=row_half_mirror (== xor4 after xor1/xor2 reduce),
// 0x140=row_mirror (== xor8 for values uniform across each 8-group).
template <int CTRL>
__device__ __forceinline__ float dpp_addf(float v) {
  int o = __builtin_amdgcn_update_dpp(0, __float_as_int(v), CTRL, 0xf, 0xf, true);
  return v + __int_as_float(o);
}
template <int CTRL>
__device__ __forceinline__ float dpp_maxf(float v) {
  int o = __builtin_amdgcn_update_dpp(0, __float_as_int(v), CTRL, 0xf, 0xf, true);
  return fmaxf(v, __int_as_float(o));
}
// ds_swizzle bit-mode: offset = (xor<<10)|0x1F. xor8=0x201F, xor16=0x401F.
template <int IMM>
__device__ __forceinline__ float swz_addf(float v) {
  int o = __builtin_amdgcn_ds_swizzle(__float_as_int(v), IMM);
  return v + __int_as_float(o);
}
template <int IMM>
__device__ __forceinline__ float swz_maxf(float v) {
  int o = __builtin_amdgcn_ds_swizzle(__float_as_int(v), IMM);
  return fmaxf(v, __int_as_float(o));
}

__global__ __launch_bounds__(256, 4) void sbm_kernel(
    const float* __restrict__ xin,    // [8192,32]
    const float* __restrict__ cen_g,  // [64,32]
    const float* __restrict__ std_g,  // [64,32]
    const float* __restrict__ w_g,    // [64]
    const float* __restrict__ noi,    // [255,8192,32]
    float* __restrict__ out)          // [8192,32]
{
  __shared__ __align__(16) float s_iv[2][KM][DIMN];  // log2e / v
  __shared__ __align__(16) float s_a [2][KM][DIMN];  // m * log2e / v
  __shared__ __align__(16) float s_c [2][KM];        // log2-domain const

  const int tid  = threadIdx.x;
  const int lane = tid & 63;
  const int dc   = lane & 7;          // d-chunk (4 dims)
  const int kg   = (lane >> 3) & 3;   // k-group (16 k)
  const int bs   = tid >> 5;          // b-slot in block, 0..7
  const int b    = blockIdx.x * 8 + bs;
  const int d0   = dc * 4;
  const int k0   = kg * 16;

  // const-gen ownership: thread -> (row gk, 8 dims at gd)
  const int gk = tid >> 2;
  const int gd = (tid & 3) * 8;

  float cen[8], s2[8];
#pragma unroll
  for (int i = 0; i < 8; ++i) {
    cen[i] = cen_g[gk * DIMN + gd + i];
    float s = std_g[gk * DIMN + gd + i];
    s2[i] = s * s;
  }
  const float lw2 = __builtin_amdgcn_logf(w_g[gk]);  // log2(w)

  float x[4];
  {
    const float4 x4 = *reinterpret_cast<const float4*>(xin + b * DIMN + d0);
    x[0] = x4.x; x[1] = x4.y; x[2] = x4.z; x[3] = x4.w;
  }

  // generate per-step constant tables for time index jj into buffer buf
  auto gen = [&](int buf, int jj) {
    const float t  = fmaf((float)(255 - jj) * (1.0f / 255.0f), (TMAXc - TMINc), TMINc);
    const float Bt = fmaf(0.5f * (BMAX - BMIN), t * t, BMIN * t);
    const float eB  = __builtin_amdgcn_exp2f(-Bt * L2E);
    const float om  = 1.0f - eB;
    const float smB = __builtin_amdgcn_sqrtf(eB);
    float cq = 0.0f, c2 = 0.0f;
    float ivv[8], av[8];
#pragma unroll
    for (int i = 0; i < 8; ++i) {
      const float v  = fmaf(eB, s2[i], om);
      const float iv = L2E * __builtin_amdgcn_rcpf(v);
      const float m  = smB * cen[i];
      const float A  = m * iv;
      ivv[i] = iv; av[i] = A;
      cq = fmaf(m, A, cq);                 // log2e * m^2 / v
      c2 += __builtin_amdgcn_logf(v);      // log2(v)
    }
    *reinterpret_cast<float4*>(&s_iv[buf][gk][gd])     = make_float4(ivv[0], ivv[1], ivv[2], ivv[3]);
    *reinterpret_cast<float4*>(&s_iv[buf][gk][gd + 4]) = make_float4(ivv[4], ivv[5], ivv[6], ivv[7]);
    *reinterpret_cast<float4*>(&s_a [buf][gk][gd])     = make_float4(av[0], av[1], av[2], av[3]);
    *reinterpret_cast<float4*>(&s_a [buf][gk][gd + 4]) = make_float4(av[4], av[5], av[6], av[7]);
    cq = dpp_addf<0xB1>(cq); cq = dpp_addf<0x4E>(cq);
    c2 = dpp_addf<0xB1>(c2); c2 = dpp_addf<0x4E>(c2);
    if ((tid & 3) == 0)
      s_c[buf][gk] = fmaf(-16.0f, c2, fmaf(-0.5f, cq, lw2));
  };

  gen(0, 0);
  __syncthreads();

#pragma unroll 1
  for (int j = 0; j < NST; ++j) {
    const int buf = j & 1;

    // noise prefetch (latency overlaps const-gen + pass1)
    const float4 z = *reinterpret_cast<const float4*>(
        noi + ((size_t)j * BD + b) * (size_t)DIMN + d0);

    // pipelined const-gen for the NEXT step into the other buffer
    if (j + 1 < NST) gen(buf ^ 1, j + 1);

    const float t  = fmaf((float)(255 - j) * (1.0f / 255.0f), (TMAXc - TMINc), TMINc);
    const float tn = fmaf((float)(254 - j) * (1.0f / 255.0f), (TMAXc - TMINc), TMINc);
    const float dt = tn - t;                        // negative
    const float bt = fmaf(BMAX - BMIN, t, BMIN);

    float h[4];
#pragma unroll
    for (int i = 0; i < 4; ++i) h[i] = -0.5f * x[i] * x[i];

    // preload this k-group's 16 c values (4x b128)
    float carr[16];
    {
      const float4 c0 = *reinterpret_cast<const float4*>(&s_c[buf][k0]);
      const float4 c1 = *reinterpret_cast<const float4*>(&s_c[buf][k0 + 4]);
      const float4 c2v = *reinterpret_cast<const float4*>(&s_c[buf][k0 + 8]);
      const float4 c3 = *reinterpret_cast<const float4*>(&s_c[buf][k0 + 12]);
      carr[0]=c0.x; carr[1]=c0.y; carr[2]=c0.z; carr[3]=c0.w;
      carr[4]=c1.x; carr[5]=c1.y; carr[6]=c1.z; carr[7]=c1.w;
      carr[8]=c2v.x; carr[9]=c2v.y; carr[10]=c2v.z; carr[11]=c2v.w;
      carr[12]=c3.x; carr[13]=c3.y; carr[14]=c3.z; carr[15]=c3.w;
    }

    // ---- pass 1: logc + max (no exp) ----
    float p[16];
    float M = -__builtin_inff();
#pragma unroll
    for (int kk = 0; kk < 16; ++kk) {
      const int k = k0 + kk;
      const float4 iv4 = *reinterpret_cast<const float4*>(&s_iv[buf][k][d0]);
      const float4 a4  = *reinterpret_cast<const float4*>(&s_a[buf][k][d0]);
      float pp = h[0] * iv4.x;
      pp = fmaf(x[0], a4.x, pp);
      pp = fmaf(h[1], iv4.y, pp);
      pp = fmaf(x[1], a4.y, pp);
      pp = fmaf(h[2], iv4.z, pp);
      pp = fmaf(x[2], a4.z, pp);
      pp = fmaf(h[3], iv4.w, pp);
      pp = fmaf(x[3], a4.w, pp);
      pp = dpp_addf<0xB1>(pp);     // xor1
      pp = dpp_addf<0x4E>(pp);     // xor2
      pp = dpp_addf<0x141>(pp);    // xor4 (row_half_mirror)
      pp += carr[kk];
      p[kk] = pp;
      M = fmaxf(M, pp);
    }
    // global max across the 4 k-groups (M is uniform across the 8 d-lanes)
    M = dpp_maxf<0x140>(M);        // row_mirror == xor8 here
    M = swz_maxf<0x401F>(M);       // xor16

    // ---- pass 2: exp2 + accumulate (no rescale) ----
    float L = 0.0f;
    float SIV[4] = {0.f, 0.f, 0.f, 0.f};
    float SA [4] = {0.f, 0.f, 0.f, 0.f};
#pragma unroll
    for (int kk = 0; kk < 16; ++kk) {
      const int k = k0 + kk;
      const float4 iv4 = *reinterpret_cast<const float4*>(&s_iv[buf][k][d0]);
      const float4 a4  = *reinterpret_cast<const float4*>(&s_a[buf][k][d0]);
      const float e = __builtin_amdgcn_exp2f(p[kk] - M);
      L += e;
      SIV[0] = fmaf(e, iv4.x, SIV[0]);
      SIV[1] = fmaf(e, iv4.y, SIV[1]);
      SIV[2] = fmaf(e, iv4.z, SIV[2]);
      SIV[3] = fmaf(e, iv4.w, SIV[3]);
      SA[0]  = fmaf(e, a4.x, SA[0]);
      SA[1]  = fmaf(e, a4.y, SA[1]);
      SA[2]  = fmaf(e, a4.z, SA[2]);
      SA[3]  = fmaf(e, a4.w, SA[3]);
    }

    // ---- merge the 4 k-groups (pure adds; M already global) ----
    L = swz_addf<0x201F>(L);
#pragma unroll
    for (int i = 0; i < 4; ++i) { SIV[i] = swz_addf<0x201F>(SIV[i]); SA[i] = swz_addf<0x201F>(SA[i]); }
    L = swz_addf<0x401F>(L);
#pragma unroll
    for (int i = 0; i < 4; ++i) { SIV[i] = swz_addf<0x401F>(SIV[i]); SA[i] = swz_addf<0x401F>(SA[i]); }

    // ---- Euler-Maruyama update ----
    // score = (SA - x*SIV) / (log2e * L); x' = cA*x + (-bt*dt)*score + sq*z
    const float invL = __builtin_amdgcn_rcpf(L);
    const float cA   = fmaf(-0.5f * bt, dt, 1.0f);
    const float cb2  = ((-bt * dt) * LN2) * invL;
    const float sq   = __builtin_amdgcn_sqrtf(bt) * __builtin_amdgcn_sqrtf(-dt);
    const float zc[4] = {z.x, z.y, z.z, z.w};
#pragma unroll
    for (int i = 0; i < 4; ++i) {
      const float u = fmaf(-x[i], SIV[i], SA[i]);
      x[i] = fmaf(cb2, u, fmaf(cA, x[i], sq * zc[i]));
    }

    __syncthreads();  // one barrier/step: protects both buffers' hand-off
  }

  if (kg == 0) {
    *reinterpret_cast<float4*>(out + b * DIMN + d0) =
        make_float4(x[0], x[1], x[2], x[3]);
  }
}

}  // namespace

extern "C" void kernel_launch(void* const* d_in, const int* in_sizes, int n_in,
                              void* d_out, int out_size, void* d_ws, size_t ws_size,
                              hipStream_t stream) {
  const float* x_init  = (const float*)d_in[0];
  const float* centers = (const float*)d_in[1];
  const float* stds    = (const float*)d_in[2];
  const float* weights = (const float*)d_in[3];
  const float* noise   = (const float*)d_in[4];
  float* out = (float*)d_out;

  sbm_kernel<<<dim3(1024), dim3(256), 0, stream>>>(x_init, centers, stds, weights,
                                                   noise, out);
}

// Round 3
// 1198.767 us; speedup vs baseline: 2.6586x; 2.6586x over previous
//
#include <hip/hip_runtime.h>
#include <math.h>

// ExactContinuousSBM: reverse VP-SDE sampling of a Gaussian mixture.
// Round 3: k-split across WAVES (not lanes) -> conflict-free broadcast LDS
// reads; 2 batch elems per lane -> tables read once per 2 b's; chunked
// two-pass softmax with chunk tables cached in registers; minimal cross-wave
// merge (numerator n=SA-x*SIV + (M,L)) through double-buffered LDS with a
// single barrier per step.
//
// Layout: 512 blocks x 256 threads (4 waves). Block owns 16 b's; every wave
// covers ALL 16 b's (8 d-lanes x 8 slots, 2 b per lane) and 16 of the 64 k's.

namespace {

constexpr int BD   = 8192;
constexpr int DIMN = 32;
constexpr int KM   = 64;
constexpr int NST  = 255;
constexpr float TMINc = 1e-4f, TMAXc = 1.0f;
constexpr float BMIN = 0.1f,  BMAX = 20.0f;
constexpr float L2E = 1.4426950408889634f;   // log2(e)
constexpr float LN2 = 0.6931471805599453f;

// DPP butterfly add over the 8 d-lanes of a slot:
// 0xB1 = quad_perm xor1, 0x4E = quad_perm xor2, 0x141 = row_half_mirror.
template <int CTRL>
__device__ __forceinline__ float dpp_addf(float v) {
  int o = __builtin_amdgcn_update_dpp(0, __float_as_int(v), CTRL, 0xf, 0xf, true);
  return v + __int_as_float(o);
}
__device__ __forceinline__ float dred8(float v) {
  v = dpp_addf<0xB1>(v);
  v = dpp_addf<0x4E>(v);
  v = dpp_addf<0x141>(v);
  return v;
}

__global__ __launch_bounds__(256, 2) void sbm_kernel(
    const float* __restrict__ xin,    // [8192,32]
    const float* __restrict__ cen_g,  // [64,32]
    const float* __restrict__ std_g,  // [64,32]
    const float* __restrict__ w_g,    // [64]
    const float* __restrict__ noi,    // [255,8192,32]
    float* __restrict__ out)          // [8192,32]
{
  __shared__ __align__(16) float s_iv[2][KM][DIMN];   // log2e / v
  __shared__ __align__(16) float s_a [2][KM][DIMN];   // m * log2e / v
  __shared__ __align__(16) float s_c [2][KM];         // log2-domain const
  __shared__ __align__(16) float4 s_n [2][4][2][64];  // per-wave numerators
  __shared__ float2 s_ml[2][4][2][8];                 // per-wave (M, L)

  const int tid  = threadIdx.x;
  const int w    = tid >> 6;        // wave 0..3 -> k range
  const int lane = tid & 63;
  const int dc   = lane & 7;        // d-chunk (4 dims)
  const int slot = lane >> 3;       // b slot 0..7
  const int d0   = dc * 4;
  const int k0   = w * 16;
  const int b0   = blockIdx.x * 16 + slot;
  const int b1   = b0 + 8;

  // const-gen ownership: thread -> (k-row gk, 8 dims at gd)
  const int gk = tid >> 2;
  const int gd = (tid & 3) * 8;

  float cen[8], s2[8];
#pragma unroll
  for (int i = 0; i < 8; ++i) {
    cen[i] = cen_g[gk * DIMN + gd + i];
    float s = std_g[gk * DIMN + gd + i];
    s2[i] = s * s;
  }
  const float lw2 = __builtin_amdgcn_logf(w_g[gk]);   // log2(w)

  float x0[4], x1[4];
  {
    const float4 a = *reinterpret_cast<const float4*>(xin + b0 * DIMN + d0);
    const float4 b = *reinterpret_cast<const float4*>(xin + b1 * DIMN + d0);
    x0[0]=a.x; x0[1]=a.y; x0[2]=a.z; x0[3]=a.w;
    x1[0]=b.x; x1[1]=b.y; x1[2]=b.z; x1[3]=b.w;
  }

  auto gen = [&](int buf, int jj) {
    const float t  = fmaf((float)(255 - jj) * (1.0f / 255.0f), (TMAXc - TMINc), TMINc);
    const float Bt = fmaf(0.5f * (BMAX - BMIN), t * t, BMIN * t);
    const float eB  = __builtin_amdgcn_exp2f(-Bt * L2E);
    const float om  = 1.0f - eB;
    const float smB = __builtin_amdgcn_sqrtf(eB);
    float cq = 0.0f, c2 = 0.0f;
    float ivv[8], av[8];
#pragma unroll
    for (int i = 0; i < 8; ++i) {
      const float v  = fmaf(eB, s2[i], om);
      const float iv = L2E * __builtin_amdgcn_rcpf(v);
      const float m  = smB * cen[i];
      const float A  = m * iv;
      ivv[i] = iv; av[i] = A;
      cq = fmaf(m, A, cq);                 // log2e * m^2/v
      c2 += __builtin_amdgcn_logf(v);      // log2 v
    }
    *reinterpret_cast<float4*>(&s_iv[buf][gk][gd])     = make_float4(ivv[0], ivv[1], ivv[2], ivv[3]);
    *reinterpret_cast<float4*>(&s_iv[buf][gk][gd + 4]) = make_float4(ivv[4], ivv[5], ivv[6], ivv[7]);
    *reinterpret_cast<float4*>(&s_a [buf][gk][gd])     = make_float4(av[0], av[1], av[2], av[3]);
    *reinterpret_cast<float4*>(&s_a [buf][gk][gd + 4]) = make_float4(av[4], av[5], av[6], av[7]);
    float q1 = dpp_addf<0xB1>(cq); q1 = dpp_addf<0x4E>(q1);
    float q2 = dpp_addf<0xB1>(c2); q2 = dpp_addf<0x4E>(q2);
    if ((tid & 3) == 0)
      s_c[buf][gk] = fmaf(-16.0f, q2, fmaf(-0.5f, q1, lw2));
  };

  gen(0, 0);
  __syncthreads();

#pragma unroll 1
  for (int j = 0; j < NST; ++j) {
    const int buf = j & 1;

    // noise prefetch (consumed at end of step -> max latency hiding)
    const float4 z0 = *reinterpret_cast<const float4*>(
        noi + ((size_t)j * BD + b0) * (size_t)DIMN + d0);
    const float4 z1 = *reinterpret_cast<const float4*>(
        noi + ((size_t)j * BD + b1) * (size_t)DIMN + d0);

    if (j + 1 < NST) gen(buf ^ 1, j + 1);   // tables for next step

    const float t  = fmaf((float)(255 - j) * (1.0f / 255.0f), (TMAXc - TMINc), TMINc);
    const float tn = fmaf((float)(254 - j) * (1.0f / 255.0f), (TMAXc - TMINc), TMINc);
    const float dt = tn - t;                 // negative
    const float bt = fmaf(BMAX - BMIN, t, BMIN);

    float h0[4], h1[4];
#pragma unroll
    for (int i = 0; i < 4; ++i) { h0[i] = -0.5f * x0[i] * x0[i]; h1[i] = -0.5f * x1[i] * x1[i]; }

    float M0 = -__builtin_inff(), M1 = -__builtin_inff();
    float L0 = 0.0f, L1 = 0.0f;
    float SIV0[4] = {0,0,0,0}, SA0[4] = {0,0,0,0};
    float SIV1[4] = {0,0,0,0}, SA1[4] = {0,0,0,0};

#pragma unroll
    for (int c = 0; c < 2; ++c) {
      const int kc = k0 + c * 8;
      // chunk constants
      const float4 ccl = *reinterpret_cast<const float4*>(&s_c[buf][kc]);
      const float4 cch = *reinterpret_cast<const float4*>(&s_c[buf][kc + 4]);
      const float cc[8] = {ccl.x, ccl.y, ccl.z, ccl.w, cch.x, cch.y, cch.z, cch.w};

      float4 tiv[8], ta[8];
      float p0[8], p1[8];
      float cm0 = -__builtin_inff(), cm1 = -__builtin_inff();
#pragma unroll
      for (int kk = 0; kk < 8; ++kk) {
        tiv[kk] = *reinterpret_cast<const float4*>(&s_iv[buf][kc + kk][d0]);
        ta[kk]  = *reinterpret_cast<const float4*>(&s_a [buf][kc + kk][d0]);
        float pa = h0[0] * tiv[kk].x;
        pa = fmaf(x0[0], ta[kk].x, pa);
        pa = fmaf(h0[1], tiv[kk].y, pa);
        pa = fmaf(x0[1], ta[kk].y, pa);
        pa = fmaf(h0[2], tiv[kk].z, pa);
        pa = fmaf(x0[2], ta[kk].z, pa);
        pa = fmaf(h0[3], tiv[kk].w, pa);
        pa = fmaf(x0[3], ta[kk].w, pa);
        float pb = h1[0] * tiv[kk].x;
        pb = fmaf(x1[0], ta[kk].x, pb);
        pb = fmaf(h1[1], tiv[kk].y, pb);
        pb = fmaf(x1[1], ta[kk].y, pb);
        pb = fmaf(h1[2], tiv[kk].z, pb);
        pb = fmaf(x1[2], ta[kk].z, pb);
        pb = fmaf(h1[3], tiv[kk].w, pb);
        pb = fmaf(x1[3], ta[kk].w, pb);
        pa = dred8(pa) + cc[kk];
        pb = dred8(pb) + cc[kk];
        p0[kk] = pa; p1[kk] = pb;
        cm0 = fmaxf(cm0, pa); cm1 = fmaxf(cm1, pb);
      }
      // merge chunk into running state: one rescale per chunk
      const float nM0 = fmaxf(M0, cm0), nM1 = fmaxf(M1, cm1);
      const float al0 = __builtin_amdgcn_exp2f(M0 - nM0);   // 0 on first chunk
      const float al1 = __builtin_amdgcn_exp2f(M1 - nM1);
      M0 = nM0; M1 = nM1;
      L0 *= al0; L1 *= al1;
#pragma unroll
      for (int i = 0; i < 4; ++i) {
        SIV0[i] *= al0; SA0[i] *= al0;
        SIV1[i] *= al1; SA1[i] *= al1;
      }
#pragma unroll
      for (int kk = 0; kk < 8; ++kk) {
        const float e0 = __builtin_amdgcn_exp2f(p0[kk] - M0);
        const float e1 = __builtin_amdgcn_exp2f(p1[kk] - M1);
        L0 += e0; L1 += e1;
        SIV0[0] = fmaf(e0, tiv[kk].x, SIV0[0]);
        SIV0[1] = fmaf(e0, tiv[kk].y, SIV0[1]);
        SIV0[2] = fmaf(e0, tiv[kk].z, SIV0[2]);
        SIV0[3] = fmaf(e0, tiv[kk].w, SIV0[3]);
        SA0[0]  = fmaf(e0, ta[kk].x, SA0[0]);
        SA0[1]  = fmaf(e0, ta[kk].y, SA0[1]);
        SA0[2]  = fmaf(e0, ta[kk].z, SA0[2]);
        SA0[3]  = fmaf(e0, ta[kk].w, SA0[3]);
        SIV1[0] = fmaf(e1, tiv[kk].x, SIV1[0]);
        SIV1[1] = fmaf(e1, tiv[kk].y, SIV1[1]);
        SIV1[2] = fmaf(e1, tiv[kk].z, SIV1[2]);
        SIV1[3] = fmaf(e1, tiv[kk].w, SIV1[3]);
        SA1[0]  = fmaf(e1, ta[kk].x, SA1[0]);
        SA1[1]  = fmaf(e1, ta[kk].y, SA1[1]);
        SA1[2]  = fmaf(e1, ta[kk].z, SA1[2]);
        SA1[3]  = fmaf(e1, ta[kk].w, SA1[3]);
      }
    }

    // per-wave numerators n = SA - x*SIV  (un-scaled; scaled at merge)
    const float4 n0 = make_float4(fmaf(-x0[0], SIV0[0], SA0[0]),
                                  fmaf(-x0[1], SIV0[1], SA0[1]),
                                  fmaf(-x0[2], SIV0[2], SA0[2]),
                                  fmaf(-x0[3], SIV0[3], SA0[3]));
    const float4 n1 = make_float4(fmaf(-x1[0], SIV1[0], SA1[0]),
                                  fmaf(-x1[1], SIV1[1], SA1[1]),
                                  fmaf(-x1[2], SIV1[2], SA1[2]),
                                  fmaf(-x1[3], SIV1[3], SA1[3]));
    s_n[buf][w][0][lane] = n0;
    s_n[buf][w][1][lane] = n1;
    if (dc == 0) {
      s_ml[buf][w][0][slot] = make_float2(M0, L0);
      s_ml[buf][w][1][slot] = make_float2(M1, L1);
    }
    __syncthreads();   // single barrier/step: orders tables, n, ml hand-offs

    // ---- cross-wave merge + Euler-Maruyama update ----
    const float cA  = fmaf(-0.5f * bt, dt, 1.0f);
    const float cb0 = (-bt * dt) * LN2;
    const float sq  = __builtin_amdgcn_sqrtf(bt) * __builtin_amdgcn_sqrtf(-dt);
    const int w1 = w ^ 1, w2 = w ^ 2, w3 = w ^ 3;

    {  // b0
      const float2 mA = s_ml[buf][w1][0][slot];
      const float2 mB = s_ml[buf][w2][0][slot];
      const float2 mC = s_ml[buf][w3][0][slot];
      const float Gm = fmaxf(fmaxf(M0, mA.x), fmaxf(mB.x, mC.x));
      const float ss = __builtin_amdgcn_exp2f(M0 - Gm);
      const float sA = __builtin_amdgcn_exp2f(mA.x - Gm);
      const float sB = __builtin_amdgcn_exp2f(mB.x - Gm);
      const float sC = __builtin_amdgcn_exp2f(mC.x - Gm);
      float Lt = ss * L0;
      Lt = fmaf(sA, mA.y, Lt); Lt = fmaf(sB, mB.y, Lt); Lt = fmaf(sC, mC.y, Lt);
      const float4 nA = s_n[buf][w1][0][lane];
      const float4 nB = s_n[buf][w2][0][lane];
      const float4 nC = s_n[buf][w3][0][lane];
      float nu[4] = {ss * n0.x, ss * n0.y, ss * n0.z, ss * n0.w};
      nu[0] = fmaf(sA, nA.x, nu[0]); nu[1] = fmaf(sA, nA.y, nu[1]);
      nu[2] = fmaf(sA, nA.z, nu[2]); nu[3] = fmaf(sA, nA.w, nu[3]);
      nu[0] = fmaf(sB, nB.x, nu[0]); nu[1] = fmaf(sB, nB.y, nu[1]);
      nu[2] = fmaf(sB, nB.z, nu[2]); nu[3] = fmaf(sB, nB.w, nu[3]);
      nu[0] = fmaf(sC, nC.x, nu[0]); nu[1] = fmaf(sC, nC.y, nu[1]);
      nu[2] = fmaf(sC, nC.z, nu[2]); nu[3] = fmaf(sC, nC.w, nu[3]);
      const float cb2 = cb0 * __builtin_amdgcn_rcpf(Lt);
      const float zc[4] = {z0.x, z0.y, z0.z, z0.w};
#pragma unroll
      for (int i = 0; i < 4; ++i)
        x0[i] = fmaf(cb2, nu[i], fmaf(cA, x0[i], sq * zc[i]));
    }
    {  // b1
      const float2 mA = s_ml[buf][w1][1][slot];
      const float2 mB = s_ml[buf][w2][1][slot];
      const float2 mC = s_ml[buf][w3][1][slot];
      const float Gm = fmaxf(fmaxf(M1, mA.x), fmaxf(mB.x, mC.x));
      const float ss = __builtin_amdgcn_exp2f(M1 - Gm);
      const float sA = __builtin_amdgcn_exp2f(mA.x - Gm);
      const float sB = __builtin_amdgcn_exp2f(mB.x - Gm);
      const float sC = __builtin_amdgcn_exp2f(mC.x - Gm);
      float Lt = ss * L1;
      Lt = fmaf(sA, mA.y, Lt); Lt = fmaf(sB, mB.y, Lt); Lt = fmaf(sC, mC.y, Lt);
      const float4 nA = s_n[buf][w1][1][lane];
      const float4 nB = s_n[buf][w2][1][lane];
      const float4 nC = s_n[buf][w3][1][lane];
      float nu[4] = {ss * n1.x, ss * n1.y, ss * n1.z, ss * n1.w};
      nu[0] = fmaf(sA, nA.x, nu[0]); nu[1] = fmaf(sA, nA.y, nu[1]);
      nu[2] = fmaf(sA, nA.z, nu[2]); nu[3] = fmaf(sA, nA.w, nu[3]);
      nu[0] = fmaf(sB, nB.x, nu[0]); nu[1] = fmaf(sB, nB.y, nu[1]);
      nu[2] = fmaf(sB, nB.z, nu[2]); nu[3] = fmaf(sB, nB.w, nu[3]);
      nu[0] = fmaf(sC, nC.x, nu[0]); nu[1] = fmaf(sC, nC.y, nu[1]);
      nu[2] = fmaf(sC, nC.z, nu[2]); nu[3] = fmaf(sC, nC.w, nu[3]);
      const float cb2 = cb0 * __builtin_amdgcn_rcpf(Lt);
      const float zc[4] = {z1.x, z1.y, z1.z, z1.w};
#pragma unroll
      for (int i = 0; i < 4; ++i)
        x1[i] = fmaf(cb2, nu[i], fmaf(cA, x1[i], sq * zc[i]));
    }
  }

  if (w == 0) {   // x replicated across waves; one writer
    *reinterpret_cast<float4*>(out + b0 * DIMN + d0) = make_float4(x0[0], x0[1], x0[2], x0[3]);
    *reinterpret_cast<float4*>(out + b1 * DIMN + d0) = make_float4(x1[0], x1[1], x1[2], x1[3]);
  }
}

}  // namespace

extern "C" void kernel_launch(void* const* d_in, const int* in_sizes, int n_in,
                              void* d_out, int out_size, void* d_ws, size_t ws_size,
                              hipStream_t stream) {
  const float* x_init  = (const float*)d_in[0];
  const float* centers = (const float*)d_in[1];
  const float* stds    = (const float*)d_in[2];
  const float* weights = (const float*)d_in[3];
  const float* noise   = (const float*)d_in[4];
  float* out = (float*)d_out;

  sbm_kernel<<<dim3(512), dim3(256), 0, stream>>>(x_init, centers, stds, weights,
                                                  noise, out);
}